// Round 6
// baseline (199.595 us; speedup 1.0000x reference)
//
#include <hip/hip_runtime.h>
#include <math.h>

#define B_ 2
#define N_ 400
#define F_ 246
#define C_ 32
#define LBL_ 1440
#define NODE_IN_ 310   // F + 2C
#define RT_ 8          // row tile for k_out

// ---------------------------------------------------------------------------
// K1: P[b,n,c] = x[b,n,:] @ W_stack[0:F, c]   (x_i term)
//     Q[b,n,c] = x[b,n,:] @ W_stack[F:2F, c]  (x_j term)
// grid = B*N blocks, 256 threads = 4 waves, k-split by wave (chain 246->62).
// xrow[k] is wave-uniform -> compiler scalarizes to s_load (SMEM pipe);
// NO LDS in the hot loop (LDS broadcast reads were the R3-R5 bottleneck).
// ---------------------------------------------------------------------------
__global__ void k_pq(const float* __restrict__ x, const float* __restrict__ Ws,
                     float* __restrict__ P, float* __restrict__ Q) {
    int row  = blockIdx.x;             // b*N + n
    int tid  = threadIdx.x;            // 0..255
    int wave = tid >> 6, lane = tid & 63;
    __shared__ float part[4][64];
    int c = lane & 31;
    const float* wbase = Ws + ((lane >> 5) ? F_ * C_ : 0) + c;
    const float* xrow  = x + (size_t)row * F_;
    float acc = 0.f;
    #pragma unroll 8
    for (int k = wave; k < F_; k += 4)
        acc += xrow[k] * wbase[k * C_];    // xrow[k] uniform -> s_load
    part[wave][lane] = acc;
    __syncthreads();
    if (tid < 64) {
        float tot = part[0][tid] + part[1][tid] + part[2][tid] + part[3][tid];
        ((tid >> 5) ? Q : P)[row * C_ + (tid & 31)] = tot;
    }
}

// ---------------------------------------------------------------------------
// K2: aggregation. grid = 2*B*N blocks, 256 threads = 8 groups x 32 lanes.
// No LDS staging: a/e accesses are group-uniform (1-2 cache lines per load,
// L1-hot: a-row 1.6 KB, e-row 1.6 KB, e-col 25.6 KB of lines). All four
// loads per m-iter are unconditional so unroll 4 keeps 16 loads in flight.
// ---------------------------------------------------------------------------
__global__ void k_agg(const float* __restrict__ a, const float* __restrict__ e,
                      const float* __restrict__ Ws, const float* __restrict__ bs,
                      const float* __restrict__ alpha,
                      const float* __restrict__ Wai, const float* __restrict__ bai,
                      const float* __restrict__ Waj, const float* __restrict__ baj,
                      const float* __restrict__ P, const float* __restrict__ Q,
                      float* __restrict__ AGGI, float* __restrict__ AGGJ) {
    int blk  = blockIdx.x;
    int mode = (blk >= B_ * N_) ? 1 : 0;
    int row  = mode ? blk - B_ * N_ : blk;   // b*N + n
    int b = row / N_, n = row % N_;
    int tid = threadIdx.x;
    int c = tid & 31, g = tid >> 5;

    float w3  = Ws[(2 * F_) * C_ + c];       // weight row for e_ij
    float w4  = Ws[(2 * F_ + 1) * C_ + c];   // weight row for e_ji
    float bsc = bs[c];
    float alc = alpha[c];
    float wat = mode ? Waj[c] : Wai[c];
    float bat = mode ? baj[0] : bai[0];

    // mode 0: own = P[b,i=n,:], other(m) = Q[b,m,:] (m = j)
    // mode 1: own = Q[b,j=n,:], other(m) = P[b,m,:] (m = i)
    float ownc = ((mode ? Q : P) + row * C_)[c];
    const float* oth = (mode ? P : Q) + b * N_ * C_ + c;

    const float* abase = a + (size_t)b * N_ * N_;
    const float* ebase = e + (size_t)b * N_ * N_;

    float acc = 0.f;
    #pragma unroll 4
    for (int m = g; m < N_; m += 8) {
        float aij  = mode ? abase[m * N_ + n] : abase[n * N_ + m];
        float er   = ebase[n * N_ + m];      // e[n, m]
        float ec   = ebase[m * N_ + n];      // e[m, n]
        float othv = oth[m * C_];
        if (aij != 0.f) {                    // uniform across the 32-lane group
            float eij = mode ? ec : er;
            float eji = mode ? er : ec;
            float raw = ownc + othv + eij * w3 + eji * w4 + bsc;
            float s = (raw >= 0.f ? raw : alc * raw) * aij;  // PReLU then mask
            float t = s * wat;               // butterfly dot over 32 channels
            t += __shfl_xor(t, 1, 32);
            t += __shfl_xor(t, 2, 32);
            t += __shfl_xor(t, 4, 32);
            t += __shfl_xor(t, 8, 32);
            t += __shfl_xor(t, 16, 32);
            float att = 1.f / (1.f + __expf(-(t + bat)));
            acc += s * att;
        }
    }
    __shared__ float part[8][C_ + 1];
    part[g][c] = acc;
    __syncthreads();
    if (tid < C_) {
        float tot = 0.f;
        #pragma unroll
        for (int gg = 0; gg < 8; ++gg) tot += part[gg][tid];
        (mode ? AGGJ : AGGI)[row * C_ + tid] = tot;
    }
}

// ---------------------------------------------------------------------------
// K3: x_new[b,n,f] = concat(x, agg_i, agg_j) @ W_node + b_node
// grid = B*N blocks, 256 threads (thread = output col f). Row operands read
// directly from global with block-uniform indices -> scalarized s_load; the
// three concat segments are three separate loops (no branchy indexing).
// No LDS at all.
// ---------------------------------------------------------------------------
__global__ void k_node(const float* __restrict__ x, const float* __restrict__ AGGI,
                       const float* __restrict__ AGGJ, const float* __restrict__ Wn,
                       const float* __restrict__ bn, float* __restrict__ XNEW) {
    int row = blockIdx.x;
    int f   = threadIdx.x;
    if (f >= F_) return;
    const float* xrow = x    + (size_t)row * F_;
    const float* ai   = AGGI + row * C_;
    const float* aj   = AGGJ + row * C_;
    float acc = bn[f];
    const float* w = Wn + f;
    #pragma unroll 8
    for (int k = 0; k < F_; ++k)           // x segment
        acc += xrow[k] * w[k * F_];
    w = Wn + F_ * F_ + f;
    #pragma unroll 8
    for (int k = 0; k < C_; ++k)           // agg_i segment
        acc += ai[k] * w[k * F_];
    w = Wn + (F_ + C_) * F_ + f;
    #pragma unroll 8
    for (int k = 0; k < C_; ++k)           // agg_j segment
        acc += aj[k] * w[k * F_];
    XNEW[(size_t)row * F_ + f] = acc;
}

// ---------------------------------------------------------------------------
// K4: out[b,n,l] = x_new[b,n,:] @ W_out[:,l] + b_out[l]
// grid = dim3(6, 100), 512 threads: 8-row tile, 256 l-cols, 2-way f-split.
// XNEW read with block-uniform index -> s_load (no LDS xs); LDS used once
// per block for the f-half reduction, padded to avoid bank conflicts.
// ---------------------------------------------------------------------------
__global__ void k_out(const float* __restrict__ XNEW, const float* __restrict__ Wo,
                      const float* __restrict__ bo, float* __restrict__ out) {
    int ct  = blockIdx.x;            // column tile
    int rt  = blockIdx.y;            // row tile
    int tid = threadIdx.x;           // 0..511
    int half = tid >> 8, lt = tid & 255;
    int l   = ct * 256 + lt;
    int r0  = rt * RT_;
    __shared__ float part[256][RT_ + 1];   // +1 pad: stride 36B kills conflicts
    float acc[RT_];
    #pragma unroll
    for (int r = 0; r < RT_; ++r) acc[r] = 0.f;
    const float* xb = XNEW + (size_t)r0 * F_;
    if (l < LBL_) {
        const float* wcol = Wo + l;
        int f0 = half * 123, f1 = f0 + 123;      // 246 = 2*123
        #pragma unroll 4
        for (int f = f0; f < f1; ++f) {
            float w = wcol[f * LBL_];            // per-lane, coalesced 256B
            #pragma unroll
            for (int r = 0; r < RT_; ++r)
                acc[r] += xb[r * F_ + f] * w;    // uniform -> s_load
        }
    }
    if (half == 1) {
        #pragma unroll
        for (int r = 0; r < RT_; ++r) part[lt][r] = acc[r];
    }
    __syncthreads();
    if (half == 0 && l < LBL_) {
        float bv = bo[l];
        #pragma unroll
        for (int r = 0; r < RT_; ++r)
            out[(size_t)(r0 + r) * LBL_ + l] = acc[r] + part[lt][r] + bv;
    }
}

// ---------------------------------------------------------------------------
extern "C" void kernel_launch(void* const* d_in, const int* in_sizes, int n_in,
                              void* d_out, int out_size, void* d_ws, size_t ws_size,
                              hipStream_t stream) {
    const float* x   = (const float*)d_in[0];
    const float* a   = (const float*)d_in[1];
    const float* e   = (const float*)d_in[2];
    const float* Ws  = (const float*)d_in[3];
    const float* bs  = (const float*)d_in[4];
    const float* al  = (const float*)d_in[5];
    const float* Wai = (const float*)d_in[6];
    const float* bai = (const float*)d_in[7];
    const float* Waj = (const float*)d_in[8];
    const float* baj = (const float*)d_in[9];
    const float* Wn  = (const float*)d_in[10];
    const float* bn  = (const float*)d_in[11];
    const float* Wo  = (const float*)d_in[12];
    const float* bo  = (const float*)d_in[13];

    float* ws   = (float*)d_ws;
    float* P    = ws;                       // B*N*C = 25600 floats
    float* Q    = P    + B_ * N_ * C_;
    float* AGGI = Q    + B_ * N_ * C_;
    float* AGGJ = AGGI + B_ * N_ * C_;
    float* XNEW = AGGJ + B_ * N_ * C_;      // B*N*F = 196800 floats

    k_pq  <<<B_ * N_,     256, 0, stream>>>(x, Ws, P, Q);
    k_agg <<<2 * B_ * N_, 256, 0, stream>>>(a, e, Ws, bs, al, Wai, bai, Waj, baj,
                                            P, Q, AGGI, AGGJ);
    k_node<<<B_ * N_,     256, 0, stream>>>(x, AGGI, AGGJ, Wn, bn, XNEW);
    k_out <<<dim3((LBL_ + 255) / 256, (B_ * N_) / RT_), 512, 0, stream>>>(
        XNEW, Wo, bo, (float*)d_out);
}

// Round 7
// 132.188 us; speedup vs baseline: 1.5099x; 1.5099x over previous
//
#include <hip/hip_runtime.h>
#include <math.h>

#define B_ 2
#define N_ 400
#define F_ 246
#define C_ 32
#define LBL_ 1440

// Padded K dims for MFMA (multiples of 32)
#define KX_ 320   // concat row: 246 x | 32 aggi | 32 aggj | 10 zero-pad (also used for k_pq with zero-padded weights)
#define KN_ 256   // XNEW padded 246 -> 256

typedef __attribute__((ext_vector_type(8))) short bf16x8;  // 8 bf16 in 4 VGPRs
typedef __attribute__((ext_vector_type(4))) float f32x4;

__device__ __forceinline__ short f2bf(float f) {           // RNE fp32->bf16
    unsigned u = __float_as_uint(f);
    return (short)((u + 0x7FFF + ((u >> 16) & 1)) >> 16);
}

// ---------------------------------------------------------------------------
// PREP: build all bf16 staging buffers in one kernel (range-dispatched):
//   Abuf [800][320]  = [bf16(x) | zeros(74)]   (agg cols filled later)
//   W2T  [64][320]   : n<32 -> W_stack[k][n] (P); n>=32 -> W_stack[246+k][n-32] (Q); k>=246 -> 0
//   WnT  [256][320]  : W_node[k][n] transposed, zero-padded (n>=246 rows zero)
//   WoT  [1440][256] : W_out[k][n] transposed, k>=246 -> 0
// ---------------------------------------------------------------------------
#define T_ABUF (800 * KX_)
#define T_W2T  (64 * KX_)
#define T_WNT  (256 * KX_)
#define T_WOT  (LBL_ * KN_)
__global__ void k_prep(const float* __restrict__ x, const float* __restrict__ Ws,
                       const float* __restrict__ Wn, const float* __restrict__ Wo,
                       short* __restrict__ Abuf, short* __restrict__ W2T,
                       short* __restrict__ WnT, short* __restrict__ WoT) {
    int t = blockIdx.x * 256 + threadIdx.x;
    if (t < T_ABUF) {
        int row = t / KX_, k = t % KX_;
        Abuf[t] = (k < F_) ? f2bf(x[row * F_ + k]) : (short)0;
        return;
    }
    t -= T_ABUF;
    if (t < T_W2T) {
        int n = t / KX_, k = t % KX_;
        float v = 0.f;
        if (k < F_) v = (n < C_) ? Ws[k * C_ + n] : Ws[(F_ + k) * C_ + (n - C_)];
        W2T[t] = f2bf(v);
        return;
    }
    t -= T_W2T;
    if (t < T_WNT) {
        int n = t / KX_, k = t % KX_;
        float v = (n < F_ && k < F_ + 2 * C_) ? Wn[k * F_ + n] : 0.f;
        WnT[t] = f2bf(v);
        return;
    }
    t -= T_WNT;
    if (t < T_WOT) {
        int n = t / KN_, k = t % KN_;
        WoT[t] = (k < F_) ? f2bf(Wo[k * LBL_ + n]) : (short)0;
    }
}

// ---------------------------------------------------------------------------
// Shared MFMA 16x16 tile: C[16][16] = A[m0:+16, :K] * BT[n0:+16, :K]^T
// A, BT row-major bf16 with row length K (mult of 32, 16B-aligned rows).
// Layouts (HW-verified m89/m120): A[m=lane&15][k=quad*8+j]; B[k][n] with
// n=lane&15, k=quad*8+j (hence BT row n, consecutive k -> one 16B load);
// C/D: col n = lane&15, row m = quad*4 + reg.
// ---------------------------------------------------------------------------
template <int K>
__device__ __forceinline__ f32x4 mfma_tile(const short* __restrict__ A,
                                           const short* __restrict__ BT,
                                           int m0, int n0, int lane) {
    int r = lane & 15, quad = lane >> 4;
    const short* ap = A + (size_t)(m0 + r) * K + quad * 8;
    const short* bp = BT + (size_t)(n0 + r) * K + quad * 8;
    f32x4 acc = {0.f, 0.f, 0.f, 0.f};
    #pragma unroll
    for (int kk = 0; kk < K; kk += 32) {
        bf16x8 a = *(const bf16x8*)(ap + kk);
        bf16x8 b = *(const bf16x8*)(bp + kk);
        acc = __builtin_amdgcn_mfma_f32_16x16x32_bf16(a, b, acc, 0, 0, 0);
    }
    return acc;
}

// K1: PQ[800][64] = Abuf(x part) @ [Ws_P | Ws_Q]   (fp32 out, no bias)
__global__ void k_pq(const short* __restrict__ Abuf, const short* __restrict__ W2T,
                     float* __restrict__ PQ) {
    int lane = threadIdx.x;
    int m0 = blockIdx.x * 16, n0 = blockIdx.y * 16;
    f32x4 acc = mfma_tile<KX_>(Abuf, W2T, m0, n0, lane);
    int n = n0 + (lane & 15), mb = m0 + (lane >> 4) * 4;
    #pragma unroll
    for (int reg = 0; reg < 4; ++reg)
        PQ[(size_t)(mb + reg) * 64 + n] = acc[reg];
}

// ---------------------------------------------------------------------------
// K2: aggregation (sparse, fp32 VALU). grid = 2*B*N blocks, 256 thr =
// 8 groups x 32 lanes (lane = channel). Unconditional loads stay in flight;
// a-test uniform per 32-lane group.
// ---------------------------------------------------------------------------
__global__ void k_agg(const float* __restrict__ a, const float* __restrict__ e,
                      const float* __restrict__ Ws, const float* __restrict__ bs,
                      const float* __restrict__ alpha,
                      const float* __restrict__ Wai, const float* __restrict__ bai,
                      const float* __restrict__ Waj, const float* __restrict__ baj,
                      const float* __restrict__ PQ,
                      float* __restrict__ AGGI, float* __restrict__ AGGJ) {
    int blk  = blockIdx.x;
    int mode = (blk >= B_ * N_) ? 1 : 0;
    int row  = mode ? blk - B_ * N_ : blk;   // b*N + n
    int b = row / N_, n = row % N_;
    int tid = threadIdx.x;
    int c = tid & 31, g = tid >> 5;

    float w3  = Ws[(2 * F_) * C_ + c];
    float w4  = Ws[(2 * F_ + 1) * C_ + c];
    float bsc = bs[c];
    float alc = alpha[c];
    float wat = mode ? Waj[c] : Wai[c];
    float bat = mode ? baj[0] : bai[0];

    // P[r][c] = PQ[r*64+c], Q[r][c] = PQ[r*64+32+c]
    float ownc = PQ[(size_t)row * 64 + (mode ? 32 : 0) + c];
    const float* oth = PQ + (size_t)b * N_ * 64 + (mode ? 0 : 32) + c;

    const float* abase = a + (size_t)b * N_ * N_;
    const float* ebase = e + (size_t)b * N_ * N_;

    float acc = 0.f;
    #pragma unroll 4
    for (int m = g; m < N_; m += 8) {
        float aij  = mode ? abase[m * N_ + n] : abase[n * N_ + m];
        float er   = ebase[n * N_ + m];      // e[n, m]
        float ec   = ebase[m * N_ + n];      // e[m, n]
        float othv = oth[(size_t)m * 64];
        if (aij != 0.f) {                    // uniform per 32-lane group
            float eij = mode ? ec : er;
            float eji = mode ? er : ec;
            float raw = ownc + othv + eij * w3 + eji * w4 + bsc;
            float s = (raw >= 0.f ? raw : alc * raw) * aij;
            float t = s * wat;               // 32-ch butterfly dot
            t += __shfl_xor(t, 1, 32);
            t += __shfl_xor(t, 2, 32);
            t += __shfl_xor(t, 4, 32);
            t += __shfl_xor(t, 8, 32);
            t += __shfl_xor(t, 16, 32);
            float att = 1.f / (1.f + __expf(-(t + bat)));
            acc += s * att;
        }
    }
    __shared__ float part[8][C_ + 1];
    part[g][c] = acc;
    __syncthreads();
    if (tid < C_) {
        float tot = 0.f;
        #pragma unroll
        for (int gg = 0; gg < 8; ++gg) tot += part[gg][tid];
        (mode ? AGGJ : AGGI)[row * C_ + tid] = tot;
    }
}

// Fill Abuf cols 246..309 with bf16(AGGI|AGGJ)
__global__ void k_fill(const float* __restrict__ AGGI, const float* __restrict__ AGGJ,
                       short* __restrict__ Abuf) {
    int t = blockIdx.x * 256 + threadIdx.x;       // 800*64
    int row = t >> 6, c = t & 63;
    float v = (c < C_) ? AGGI[row * C_ + c] : AGGJ[row * C_ + (c - C_)];
    Abuf[(size_t)row * KX_ + F_ + c] = f2bf(v);
}

// K3: XN16[800][256] = bf16( Abuf @ WnT^T + bn ), cols >=246 zeroed
__global__ void k_node(const short* __restrict__ Abuf, const short* __restrict__ WnT,
                       const float* __restrict__ bn, short* __restrict__ XN16) {
    int lane = threadIdx.x;
    int m0 = blockIdx.x * 16, n0 = blockIdx.y * 16;
    f32x4 acc = mfma_tile<KX_>(Abuf, WnT, m0, n0, lane);
    int n = n0 + (lane & 15), mb = m0 + (lane >> 4) * 4;
    float bv = (n < F_) ? bn[n] : 0.f;
    #pragma unroll
    for (int reg = 0; reg < 4; ++reg)
        XN16[(size_t)(mb + reg) * KN_ + n] = (n < F_) ? f2bf(acc[reg] + bv) : (short)0;
}

// K4: out[800][1440] = XN16 @ WoT^T + bo   (fp32 out)
__global__ void k_out(const short* __restrict__ XN16, const short* __restrict__ WoT,
                      const float* __restrict__ bo, float* __restrict__ out) {
    int lane = threadIdx.x;
    int m0 = blockIdx.x * 16, n0 = blockIdx.y * 16;
    f32x4 acc = mfma_tile<KN_>(XN16, WoT, m0, n0, lane);
    int n = n0 + (lane & 15), mb = m0 + (lane >> 4) * 4;
    float bv = bo[n];
    #pragma unroll
    for (int reg = 0; reg < 4; ++reg)
        out[(size_t)(mb + reg) * LBL_ + n] = acc[reg] + bv;
}

// ---------------------------------------------------------------------------
extern "C" void kernel_launch(void* const* d_in, const int* in_sizes, int n_in,
                              void* d_out, int out_size, void* d_ws, size_t ws_size,
                              hipStream_t stream) {
    const float* x   = (const float*)d_in[0];
    const float* a   = (const float*)d_in[1];
    const float* e   = (const float*)d_in[2];
    const float* Ws  = (const float*)d_in[3];
    const float* bs  = (const float*)d_in[4];
    const float* al  = (const float*)d_in[5];
    const float* Wai = (const float*)d_in[6];
    const float* bai = (const float*)d_in[7];
    const float* Waj = (const float*)d_in[8];
    const float* baj = (const float*)d_in[9];
    const float* Wn  = (const float*)d_in[10];
    const float* bn  = (const float*)d_in[11];
    const float* Wo  = (const float*)d_in[12];
    const float* bo  = (const float*)d_in[13];

    // fp32 region
    float* PQ   = (float*)d_ws;                    // 800*64
    float* AGGI = PQ + 800 * 64;                   // 800*32
    float* AGGJ = AGGI + 800 * C_;                 // 800*32
    // bf16 region (16B-aligned: 102400 floats precede)
    short* Abuf = (short*)(AGGJ + 800 * C_);       // 800*320
    short* W2T  = Abuf + T_ABUF;                   // 64*320
    short* WnT  = W2T + T_W2T;                     // 256*320
    short* WoT  = WnT + T_WNT;                     // 1440*256
    short* XN16 = WoT + T_WOT;                     // 800*256

    int prep_total = T_ABUF + T_W2T + T_WNT + T_WOT;
    k_prep<<<(prep_total + 255) / 256, 256, 0, stream>>>(x, Ws, Wn, Wo,
                                                         Abuf, W2T, WnT, WoT);
    k_pq  <<<dim3(50, 4),  64, 0, stream>>>(Abuf, W2T, PQ);
    k_agg <<<2 * B_ * N_, 256, 0, stream>>>(a, e, Ws, bs, al, Wai, bai, Waj, baj,
                                            PQ, AGGI, AGGJ);
    k_fill<<<(800 * 64) / 256, 256, 0, stream>>>(AGGI, AGGJ, Abuf);
    k_node<<<dim3(50, 16), 64, 0, stream>>>(Abuf, WnT, bn, XN16);
    k_out <<<dim3(50, 90), 64, 0, stream>>>(XN16, WoT, bo, (float*)d_out);
}